// Round 24
// baseline (78.572 us; speedup 1.0000x reference)
//
#include <hip/hip_runtime.h>
#include <hip/hip_bf16.h>

typedef __attribute__((ext_vector_type(8))) short bf16x8;
typedef __attribute__((ext_vector_type(4))) float f32x4;
typedef __attribute__((ext_vector_type(4))) int i32x4;
typedef __attribute__((ext_vector_type(2))) int i32x2;
typedef __attribute__((ext_vector_type(4))) unsigned short u16x4;

// ---------- helpers ----------
static __device__ __forceinline__ void gload_lds16(const void* g, void* l) {
  __builtin_amdgcn_global_load_lds((const __attribute__((address_space(1))) void*)g,
                                   (__attribute__((address_space(3))) void*)l,
                                   16, 0, 0);
}

static __device__ __forceinline__ unsigned short f2bf(float x) {
  unsigned int u = __float_as_uint(x);
  u += 0x7fffu + ((u >> 16) & 1u);
  return (unsigned short)(u >> 16);
}
static __device__ __forceinline__ float bf2f(unsigned short u) {
  return __uint_as_float((unsigned int)u << 16);
}

// ---------------- shared BMxBN GEMM core, NT threads (NT/64 waves as (NW/2)x2)
template <int BM, int BN, int NT>
static __device__ __forceinline__ void gemm_core(
    const unsigned short* __restrict__ A, int lda,
    const unsigned short* __restrict__ Bt, int ldb,
    int kbeg, int kend, int brow, int bcol,
    unsigned short* As, unsigned short* Bs,
    f32x4 (&acc)[BM / (8 * (NT / 64))][BN / 32])
{
  constexpr int NW = NT / 64;
  constexpr int MA = BM / (8 * NW), NB = BN / 32;
  constexpr int CA = 8 * BM / NT, CB = 8 * BN / NT;  // staging chunks
  const int tid = threadIdx.x;
  const int wid = tid >> 6, lane = tid & 63;
  const int wr = wid >> 1, wc = wid & 1;
  const int l15 = lane & 15, l4 = lane >> 4;
  const int foff = tid * 8;

  for (int k0 = kbeg; k0 < kend; k0 += 64) {
#pragma unroll
    for (int c = 0; c < CA; ++c) {
      int f = c * (NT * 8) + foff;
      gload_lds16(A + (size_t)(brow + (f >> 6)) * lda + k0 + (f & 63), As + f);
    }
#pragma unroll
    for (int c = 0; c < CB; ++c) {
      int f = c * (NT * 8) + foff;
      gload_lds16(Bt + (size_t)(bcol + (f >> 6)) * ldb + k0 + (f & 63), Bs + f);
    }
    __syncthreads();
#pragma unroll
    for (int kk = 0; kk < 2; ++kk) {
      const int ko = kk * 32 + l4 * 8;
      bf16x8 af[MA], bfv[NB];
#pragma unroll
      for (int m = 0; m < MA; ++m)
        af[m] = *(const bf16x8*)(As + (wr * (16 * MA) + m * 16 + l15) * 64 + ko);
#pragma unroll
      for (int n = 0; n < NB; ++n)
        bfv[n] = *(const bf16x8*)(Bs + (wc * (BN / 2) + n * 16 + l15) * 64 + ko);
#pragma unroll
      for (int m = 0; m < MA; ++m)
#pragma unroll
        for (int n = 0; n < NB; ++n)
          acc[m][n] = __builtin_amdgcn_mfma_f32_16x16x32_bf16(af[m], bfv[n], acc[m][n], 0, 0, 0);
    }
    __syncthreads();
  }
}

// ---------------- L1: mega-prep (gated blocks compute flag locally)
__global__ __launch_bounds__(256)
void prep(const float* __restrict__ ob, int* __restrict__ flag,
          float* __restrict__ zeros,
          const float* __restrict__ mk, const float* __restrict__ mv,
          unsigned short* __restrict__ kb, unsigned short* __restrict__ mvb,
          const float* __restrict__ ow, unsigned short* __restrict__ owt,
          const float* __restrict__ q, unsigned short* __restrict__ qb,
          const float* __restrict__ upd, unsigned short* __restrict__ cat,
          const float* __restrict__ gw, unsigned short* __restrict__ gwt,
          unsigned short* __restrict__ vt)
{
  __shared__ float t[32][33];
  const int b = blockIdx.x;
  const int tid = threadIdx.x;
  if (b == 0) {
    f32x4 v = *(const f32x4*)(ob + tid * 4);
    float mx = fmaxf(fmaxf(fabsf(v[0]), fabsf(v[1])), fmaxf(fabsf(v[2]), fabsf(v[3])));
#pragma unroll
    for (int off = 32; off >= 1; off >>= 1) mx = fmaxf(mx, __shfl_xor(mx, off, 64));
    __shared__ float sm[4];
    const int wid = tid >> 6, lane = tid & 63;
    if (lane == 0) sm[wid] = mx;
    __syncthreads();
    if (tid == 0) {
      float m = fmaxf(fmaxf(sm[0], sm[1]), fmaxf(sm[2], sm[3]));
      *flag = (m != 0.0f) ? 1 : 0;
    }
  } else if (b < 17) {
    f32x4 z = {};
    *(f32x4*)(zeros + (b - 1) * 1024 + tid * 4) = z;
  } else if (b < 529) {
    int idx = (b - 17) * 256 + tid;
    const float* in; unsigned short* out; int rel;
    if (idx < 65536) { in = mk; out = kb;  rel = idx; }
    else             { in = mv; out = mvb; rel = idx - 65536; }
    size_t f = (size_t)rel * 8;
    f32x4 a = *(const f32x4*)(in + f);
    f32x4 c = *(const f32x4*)(in + f + 4);
    union { unsigned short u[8]; i32x4 vec; } pk;
#pragma unroll
    for (int i = 0; i < 4; ++i) { pk.u[i] = f2bf(a[i]); pk.u[4 + i] = f2bf(c[i]); }
    *(i32x4*)(out + f) = pk.vec;
  } else if (b < 1553) {
    int id = b - 529;
    const int bx = id & 31, by = id >> 5;
    const int tx = tid & 31, ty = tid >> 5;
    const int c0 = bx * 32, r0 = by * 32;
#pragma unroll
    for (int i = 0; i < 4; ++i)
      t[ty + i * 8][tx] = ow[(size_t)(r0 + ty + i * 8) * 1024 + c0 + tx];
    __syncthreads();
#pragma unroll
    for (int i = 0; i < 4; ++i)
      owt[(size_t)(c0 + ty + i * 8) * 1024 + r0 + tx] = f2bf(t[tx][ty + i * 8]);
  } else if (b < 5649) {
    int idx = (b - 1553) * 256 + tid;
    size_t f = (size_t)idx * 8;
    f32x4 a = *(const f32x4*)(q + f);
    f32x4 c = *(const f32x4*)(q + f + 4);
    union { unsigned short u[8]; i32x4 vec; } pk;
#pragma unroll
    for (int i = 0; i < 4; ++i) { pk.u[i] = f2bf(a[i]); pk.u[4 + i] = f2bf(c[i]); }
    *(i32x4*)(qb + f) = pk.vec;
  } else {
    // gated roles: compute the need-flag locally (no intra-launch dependency)
    f32x4 v = *(const f32x4*)(ob + tid * 4);
    float mx = fmaxf(fmaxf(fabsf(v[0]), fabsf(v[1])), fmaxf(fabsf(v[2]), fabsf(v[3])));
#pragma unroll
    for (int off = 32; off >= 1; off >>= 1) mx = fmaxf(mx, __shfl_xor(mx, off, 64));
    __shared__ float sm2[4];
    const int wid = tid >> 6, lane = tid & 63;
    if (lane == 0) sm2[wid] = mx;
    __syncthreads();
    float m = fmaxf(fmaxf(sm2[0], sm2[1]), fmaxf(sm2[2], sm2[3]));
    if (m == 0.0f) return;  // fast path: gate pipeline dead through zero out-bias
    __syncthreads();
    int g = b - 5649;
    if (g < 4096) {
      int idx = g * 256 + tid;
      size_t f = (size_t)idx * 8;
      int row = (int)(f >> 10);
      int col = (int)(f & 1023);
      f32x4 a = *(const f32x4*)(upd + f);
      f32x4 c = *(const f32x4*)(upd + f + 4);
      union { unsigned short u[8]; i32x4 vec; } pk;
#pragma unroll
      for (int i = 0; i < 4; ++i) { pk.u[i] = f2bf(a[i]); pk.u[4 + i] = f2bf(c[i]); }
      *(i32x4*)(cat + (size_t)row * 2048 + 1024 + col) = pk.vec;
    } else {
      const float* in; unsigned short* out; int R, id;
      if (g < 6144) { in = gw; out = gwt; R = 2048; id = g - 4096; }
      else          { in = mv; out = vt;  R = 512;  id = g - 6144; }
      const int bx = id & 31, by = id >> 5;
      const int tx = tid & 31, ty = tid >> 5;
      const int c0 = bx * 32, r0 = by * 32;
#pragma unroll
      for (int i = 0; i < 4; ++i)
        t[ty + i * 8][tx] = in[(size_t)(r0 + ty + i * 8) * 1024 + c0 + tx];
      __syncthreads();
#pragma unroll
      for (int i = 0; i < 4; ++i)
        out[(size_t)(c0 + ty + i * 8) * R + r0 + tx] = f2bf(t[tx][ty + i * 8]);
    }
  }
}

// ---------------- L2: scores (b<512, 8-wave blocks, VGPR<=64) + w2 tail
__global__ __launch_bounds__(512, 8)
void k_scores_w2(const unsigned short* __restrict__ qb,
                 const unsigned short* __restrict__ kb,
                 const float* __restrict__ mw,
                 unsigned short* __restrict__ probs,
                 const unsigned short* __restrict__ owt,
                 const unsigned short* __restrict__ mvb,
                 float* __restrict__ w2p)
{
  __shared__ unsigned short As[128 * 64];  // 16 KB
  __shared__ unsigned short Bs[64 * 64];   //  8 KB
  const int b = blockIdx.x;
  const int tid = threadIdx.x;
  const int wid = tid >> 6, lane = tid & 63;
  const int wr = wid >> 1, wc = wid & 1;   // wr 0..3 (32-row strips), wc 0..1
  const int l15 = lane & 15, l4 = lane >> 4;

  if (b < 512) {
    const int swz = (b & 7) * 64 + (b >> 3);   // XCD swizzle
    const int bx = swz & 7, by = swz >> 3;
    const int brow = by * 128, bcol = bx * 64;
    f32x4 acc[2][2] = {};
    gemm_core<128, 64, 512>(qb, 1024, kb, 1024, 0, 1024, brow, bcol, As, Bs, acc);

    // epilogue: exp + packed bf16 stores (adjacent-lane pair -> 4B)
#pragma unroll
    for (int m = 0; m < 2; ++m) {
#pragma unroll
      for (int j = 0; j < 4; ++j) {
        int row = brow + wr * 32 + m * 16 + l4 * 4 + j;
        const float* mwrow = mw + (size_t)row * 512;
#pragma unroll
        for (int n = 0; n < 2; ++n) {
          int col = bcol + wc * 32 + n * 16 + l15;
          float p = __expf(acc[m][n][j] * 0.08838834764831845f * mwrow[col]);
          float o = __shfl_xor(p, 1);
          if (!(lane & 1)) {
            unsigned int pw = (unsigned int)f2bf(p) | ((unsigned int)f2bf(o) << 16);
            *(unsigned int*)(probs + (size_t)row * 512 + col) = pw;
          }
        }
      }
    }
  } else {
    const int g = b - 512;                 // 0..127
    const int bx = g & 7;                  // N tile (mvb rows)
    const int by = (g >> 3) & 7;           // M tile (owt rows)
    const int bz = g >> 6;                 // K slice (0..1)
    const int brow = by * 128, bcol = bx * 64;
    f32x4 acc[2][2] = {};
    gemm_core<128, 64, 512>(owt, 1024, mvb, 1024, bz * 512, bz * 512 + 512,
                            brow, bcol, As, Bs, acc);
    float* dst = w2p + (size_t)bz * 524288;
#pragma unroll
    for (int m = 0; m < 2; ++m) {
      int row0 = brow + wr * 32 + m * 16 + l4 * 4;
#pragma unroll
      for (int j = 0; j < 4; ++j) {
#pragma unroll
        for (int n = 0; n < 2; ++n)
          dst[(size_t)(row0 + j) * 512 + bcol + wc * 32 + n * 16 + l15] = acc[m][n][j];
      }
    }
  }
}

// ---------------- L3: w2 reduce (b<512) + [flag] rowsum (b in [512,2560))
//                  + [flag] read-GEMM into cat (b >= 2560, block-local rowsums)
__global__ __launch_bounds__(256)
void k_w2red_rows_read(const float* __restrict__ w2p,
                       unsigned short* __restrict__ w2t,
                       const float* __restrict__ dec,
                       const unsigned short* __restrict__ probs,
                       float* __restrict__ rowsum,
                       const unsigned short* __restrict__ vt,
                       unsigned short* __restrict__ cat,
                       const int* __restrict__ flag)
{
  __shared__ unsigned short As[128 * 64];
  __shared__ unsigned short Bs[128 * 64];
  __shared__ float srow[128];
  const int b = blockIdx.x;
  const int tid = threadIdx.x;
  if (b < 512) {
    const int i = (b * 256 + tid) * 4;
    const float d = *dec;
    f32x4 s0 = *(const f32x4*)(w2p + i);
    f32x4 s1 = *(const f32x4*)(w2p + 524288 + i);
    union { unsigned short u[4]; i32x2 v; } pk;
#pragma unroll
    for (int j = 0; j < 4; ++j) pk.u[j] = f2bf((s0[j] + s1[j]) * d);
    *(i32x2*)(w2t + i) = pk.v;
  } else if (b < 2560) {
    if (*flag == 0) return;  // rowsum only needed on the gate (slow) path
    const int wid = tid >> 6, lane = tid & 63;
    const int row = (b - 512) * 4 + wid;
    bf16x8 v = *(const bf16x8*)(probs + (size_t)row * 512 + lane * 8);
    float s = 0.0f;
#pragma unroll
    for (int i = 0; i < 8; ++i) s += bf2f((unsigned short)v[i]);
#pragma unroll
    for (int off = 32; off >= 1; off >>= 1) s += __shfl_xor(s, off, 64);
    if (lane == 0) rowsum[row] = s;
  } else {
    if (*flag == 0) return;  // read-GEMM feeds only the gate path
    const int f = b - 2560;
    const int swz = (f & 7) * 64 + (f >> 3);
    const int bx = swz & 7, by = swz >> 3;
    const int brow = by * 128, bcol = bx * 128;
    const int wid = tid >> 6, lane = tid & 63;
    const int wr = wid >> 1, wc = wid & 1;
    const int l15 = lane & 15, l4 = lane >> 4;
    f32x4 acc[4][4] = {};
    gemm_core<128, 128, 256>(probs, 512, vt, 512, 0, 512, brow, bcol, As, Bs, acc);
    // block-local rowsums (same per-row read/reduce order as the rowsum blocks)
    for (int r = 0; r < 32; ++r) {
      int lrow = wid * 32 + r;
      bf16x8 v = *(const bf16x8*)(probs + (size_t)(brow + lrow) * 512 + lane * 8);
      float s = 0.0f;
#pragma unroll
      for (int i = 0; i < 8; ++i) s += bf2f((unsigned short)v[i]);
#pragma unroll
      for (int off = 32; off >= 1; off >>= 1) s += __shfl_xor(s, off, 64);
      if (lane == 0) srow[lrow] = s;
    }
    __syncthreads();
    const float d = *dec;
#pragma unroll
    for (int m = 0; m < 4; ++m) {
      int row0 = brow + wr * 64 + m * 16 + l4 * 4;
#pragma unroll
      for (int j = 0; j < 4; ++j) {
        int row = row0 + j;
        const float rscl = d / srow[row - brow];
#pragma unroll
        for (int n = 0; n < 4; ++n) {
          int col = bcol + wc * 64 + n * 16 + l15;
          cat[(size_t)row * 2048 + col] = f2bf(acc[m][n][j] * rscl);
        }
      }
    }
  }
}

// ---------------- L4: out-projection (b<512, 8-wave) + [flag] gate GEMM (b>=512)
__global__ __launch_bounds__(512)
void k_out_gate(const unsigned short* __restrict__ probs,
                const unsigned short* __restrict__ w2t,
                const float* __restrict__ rowsum,
                unsigned short* __restrict__ outpre,
                const unsigned short* __restrict__ cat,
                const unsigned short* __restrict__ gwt,
                const float* __restrict__ gb,
                float* __restrict__ gsum,
                const int* __restrict__ flag)
{
  __shared__ unsigned short As[128 * 64];
  __shared__ unsigned short Bs[128 * 64];
  const int b = blockIdx.x;
  const int tid = threadIdx.x;
  const int wid = tid >> 6, lane = tid & 63;
  const int wr = wid >> 1, wc = wid & 1;   // wr 0..3 (32-row strips), wc 0..1
  const int l15 = lane & 15, l4 = lane >> 4;

  if (b < 512) {
    const int swz = (b & 7) * 64 + (b >> 3);
    const int bx = swz & 7, by = swz >> 3;
    const int brow = by * 128, bcol = bx * 128;
    f32x4 acc[2][4] = {};
    gemm_core<128, 128, 512>(probs, 512, w2t, 512, 0, 512, brow, bcol, As, Bs, acc);
    const bool nf = (*flag != 0);  // slow path: outpre must be exactly normalized
#pragma unroll
    for (int m = 0; m < 2; ++m) {
      int row0 = brow + wr * 32 + m * 16 + l4 * 4;
#pragma unroll
      for (int j = 0; j < 4; ++j) {
        int row = row0 + j;
        const float rscl = nf ? (1.0f / rowsum[row]) : 1.0f;
#pragma unroll
        for (int n = 0; n < 4; ++n) {
          int col = bcol + wc * 64 + n * 16 + l15;
          float v = acc[m][n][j] * rscl;
          float o = __shfl_xor(v, 1);
          if (!(lane & 1)) {
            unsigned int pw = (unsigned int)f2bf(v) | ((unsigned int)f2bf(o) << 16);
            *(unsigned int*)(outpre + (size_t)row * 1024 + col) = pw;
          }
        }
      }
    }
  } else {
    if (*flag == 0) return;
    const int f = b - 512;
    const int swz = (f & 7) * 64 + (f >> 3);
    const int bx = swz & 7, by = swz >> 3;
    const int brow = by * 128, bcol = bx * 128;
    f32x4 acc[2][4] = {};
    gemm_core<128, 128, 512>(cat, 2048, gwt, 2048, 0, 2048, brow, bcol, As, Bs, acc);
#pragma unroll
    for (int m = 0; m < 2; ++m) {
#pragma unroll
      for (int j = 0; j < 4; ++j) {
        float part = 0.0f;
#pragma unroll
        for (int n = 0; n < 4; ++n) {
          int col = bcol + wc * 64 + n * 16 + l15;
          float x = acc[m][n][j] + gb[col];
          part += 1.0f / (1.0f + __expf(-x));
        }
#pragma unroll
        for (int off = 1; off < 16; off <<= 1)
          part += __shfl_xor(part, off, 64);
        if (l15 == 0) {
          int row = brow + wr * 32 + m * 16 + l4 * 4 + j;
          atomicAdd(&gsum[row], part);
        }
      }
    }
  }
}

// ---------------- L5: LayerNorm, 4 rows per 1024-thread block
// Identical per-thread element mapping and per-row reduce tree as the proven
// 1-row/256-thread version -> bit-identical output, 1/4 the blocks.
__global__ __launch_bounds__(1024)
void ln_rows(const unsigned short* __restrict__ X, const float* __restrict__ gsum,
             const float* __restrict__ ob,
             const float* __restrict__ gamma, const float* __restrict__ beta,
             float* __restrict__ Y)
{
  const int tid = threadIdx.x;
  const int r = tid >> 8;                   // row within block (0..3)
  const int ct = tid & 255;                 // thread within row (0..255)
  const int row = blockIdx.x * 4 + r;
  const size_t base = (size_t)row * 1024 + ct * 4;
  const float scl = 1.0f + gsum[row] * (1.0f / 1024.0f);
  u16x4 xr = *(const u16x4*)(X + base);
  f32x4 bo = *(const f32x4*)(ob + ct * 4);
  float x[4];
#pragma unroll
  for (int i = 0; i < 4; ++i) x[i] = bf2f(xr[i]) * scl + bo[i];
  float s = x[0] + x[1] + x[2] + x[3];
  float q = x[0] * x[0] + x[1] * x[1] + x[2] * x[2] + x[3] * x[3];
#pragma unroll
  for (int off = 32; off >= 1; off >>= 1) {
    s += __shfl_xor(s, off, 64);
    q += __shfl_xor(q, off, 64);
  }
  __shared__ float ss[16], qq[16];
  const int wid = tid >> 6, lane = tid & 63;  // wid 0..15; row r owns waves 4r..4r+3
  if (lane == 0) { ss[wid] = s; qq[wid] = q; }
  __syncthreads();
  s = ss[r * 4 + 0] + ss[r * 4 + 1] + ss[r * 4 + 2] + ss[r * 4 + 3];
  q = qq[r * 4 + 0] + qq[r * 4 + 1] + qq[r * 4 + 2] + qq[r * 4 + 3];
  const float mu = s * (1.0f / 1024.0f);
  const float var = q * (1.0f / 1024.0f) - mu * mu;
  const float rr = rsqrtf(var + 1e-5f);
  f32x4 g = *(const f32x4*)(gamma + ct * 4);
  f32x4 bt = *(const f32x4*)(beta + ct * 4);
  f32x4 y;
#pragma unroll
  for (int i = 0; i < 4; ++i) y[i] = (x[i] - mu) * rr * g[i] + bt[i];
  *(f32x4*)(Y + base) = y;
}

// ---------------- launch ----------------
extern "C" void kernel_launch(void* const* d_in, const int* in_sizes, int n_in,
                              void* d_out, int out_size, void* d_ws, size_t ws_size,
                              hipStream_t stream)
{
  (void)in_sizes; (void)n_in; (void)out_size; (void)ws_size;
  const float* q   = (const float*)d_in[0];   // [8192,1024]
  const float* mw  = (const float*)d_in[1];   // [8192,512]
  const float* upd = (const float*)d_in[2];   // [8192,1024]
  const float* mk  = (const float*)d_in[3];   // [512,1024]
  const float* mv  = (const float*)d_in[4];   // [512,1024]
  const float* dec = (const float*)d_in[5];   // scalar
  const float* gw  = (const float*)d_in[6];   // [2048,1024]
  const float* gb  = (const float*)d_in[7];   // [1024]
  const float* ow  = (const float*)d_in[8];   // [1024,1024]
  const float* ob  = (const float*)d_in[9];   // [1024]
  const float* lg  = (const float*)d_in[10];  // [1024]
  const float* lb  = (const float*)d_in[11];  // [1024]
  float* outp = (float*)d_out;
  char* ws = (char*)d_ws;

  // workspace layout (bytes)
  unsigned short* qb     = (unsigned short*)(ws + 0);          // 16.78 MB
  unsigned short* probs  = (unsigned short*)(ws + 16777216);   // 8.39 MB
  unsigned short* outpre = (unsigned short*)(ws + 25165824);   // 16.78 MB
  unsigned short* kb     = (unsigned short*)(ws + 41943040);   // 1.05 MB
  unsigned short* mvb    = (unsigned short*)(ws + 42991616);   // 1.05 MB
  unsigned short* owt    = (unsigned short*)(ws + 44040192);   // 2.10 MB
  unsigned short* w2t    = (unsigned short*)(ws + 46137344);   // 1.05 MB
  float*          w2p    = (float*)(ws + 47185920);            // 4.19 MB (2 slices)
  unsigned short* vt     = (unsigned short*)(ws + 51380224);   // 1.05 MB (flag path)
  unsigned short* gwt    = (unsigned short*)(ws + 52428800);   // 4.19 MB (flag path)
  unsigned short* cat    = (unsigned short*)(ws + 56623104);   // 33.55 MB (flag path)
  float*          gsum   = (float*)(ws + 90177536);            // 32 KB
  float*          rowsum = (float*)(ws + 90210304);            // 32 KB
  int*            flag   = (int*)(ws + 90243072);              // 4 B
  // total ~90.3 MB

  // 1) prep: flag, zeroing, kb/mvb cvt, ow transpose, q cvt (+gated roles)
  prep<<<12305, 256, 0, stream>>>(ob, flag, gsum, mk, mv, kb, mvb, ow, owt,
                                  q, qb, upd, cat, gw, gwt, vt);
  // 2) scores (8-wave, VGPR<=64 -> 32 waves/CU) + w2 split-K tail
  k_scores_w2<<<640, 512, 0, stream>>>(qb, kb, mw, probs, owt, mvb, w2p);
  // 3) w2 reduce + [flag] rowsum + [flag] read-GEMM into cat
  k_w2red_rows_read<<<3072, 256, 0, stream>>>(w2p, w2t, dec, probs, rowsum,
                                              vt, cat, flag);
  // 4) out-projection (unnormalized on fast path) + [flag] gate rowsums
  k_out_gate<<<1024, 512, 0, stream>>>(probs, w2t, rowsum, outpre, cat, gwt,
                                       gb, gsum, flag);
  // 5) LayerNorm (gate scale [=1 when skipped] + out bias fused) -> final output
  ln_rows<<<2048, 1024, 0, stream>>>(outpre, gsum, ob, lg, lb, outp);
}

// Round 25
// 76.892 us; speedup vs baseline: 1.0219x; 1.0219x over previous
//
#include <hip/hip_runtime.h>
#include <hip/hip_bf16.h>

typedef __attribute__((ext_vector_type(8))) short bf16x8;
typedef __attribute__((ext_vector_type(4))) float f32x4;
typedef __attribute__((ext_vector_type(4))) int i32x4;
typedef __attribute__((ext_vector_type(2))) int i32x2;
typedef __attribute__((ext_vector_type(4))) unsigned short u16x4;

// ---------- helpers ----------
static __device__ __forceinline__ void gload_lds16(const void* g, void* l) {
  __builtin_amdgcn_global_load_lds((const __attribute__((address_space(1))) void*)g,
                                   (__attribute__((address_space(3))) void*)l,
                                   16, 0, 0);
}

static __device__ __forceinline__ unsigned short f2bf(float x) {
  unsigned int u = __float_as_uint(x);
  u += 0x7fffu + ((u >> 16) & 1u);
  return (unsigned short)(u >> 16);
}
static __device__ __forceinline__ float bf2f(unsigned short u) {
  return __uint_as_float((unsigned int)u << 16);
}

// ---------------- shared BMxBN GEMM core, NT threads (NT/64 waves as (NW/2)x2)
template <int BM, int BN, int NT>
static __device__ __forceinline__ void gemm_core(
    const unsigned short* __restrict__ A, int lda,
    const unsigned short* __restrict__ Bt, int ldb,
    int kbeg, int kend, int brow, int bcol,
    unsigned short* As, unsigned short* Bs,
    f32x4 (&acc)[BM / (8 * (NT / 64))][BN / 32])
{
  constexpr int NW = NT / 64;
  constexpr int MA = BM / (8 * NW), NB = BN / 32;
  constexpr int CA = 8 * BM / NT, CB = 8 * BN / NT;  // staging chunks
  const int tid = threadIdx.x;
  const int wid = tid >> 6, lane = tid & 63;
  const int wr = wid >> 1, wc = wid & 1;
  const int l15 = lane & 15, l4 = lane >> 4;
  const int foff = tid * 8;

  for (int k0 = kbeg; k0 < kend; k0 += 64) {
#pragma unroll
    for (int c = 0; c < CA; ++c) {
      int f = c * (NT * 8) + foff;
      gload_lds16(A + (size_t)(brow + (f >> 6)) * lda + k0 + (f & 63), As + f);
    }
#pragma unroll
    for (int c = 0; c < CB; ++c) {
      int f = c * (NT * 8) + foff;
      gload_lds16(Bt + (size_t)(bcol + (f >> 6)) * ldb + k0 + (f & 63), Bs + f);
    }
    __syncthreads();
#pragma unroll
    for (int kk = 0; kk < 2; ++kk) {
      const int ko = kk * 32 + l4 * 8;
      bf16x8 af[MA], bfv[NB];
#pragma unroll
      for (int m = 0; m < MA; ++m)
        af[m] = *(const bf16x8*)(As + (wr * (16 * MA) + m * 16 + l15) * 64 + ko);
#pragma unroll
      for (int n = 0; n < NB; ++n)
        bfv[n] = *(const bf16x8*)(Bs + (wc * (BN / 2) + n * 16 + l15) * 64 + ko);
#pragma unroll
      for (int m = 0; m < MA; ++m)
#pragma unroll
        for (int n = 0; n < NB; ++n)
          acc[m][n] = __builtin_amdgcn_mfma_f32_16x16x32_bf16(af[m], bfv[n], acc[m][n], 0, 0, 0);
    }
    __syncthreads();
  }
}

// ---------------- L1: mega-prep (gated blocks compute flag locally)
__global__ __launch_bounds__(256)
void prep(const float* __restrict__ ob, int* __restrict__ flag,
          float* __restrict__ zeros,
          const float* __restrict__ mk, const float* __restrict__ mv,
          unsigned short* __restrict__ kb, unsigned short* __restrict__ mvb,
          const float* __restrict__ ow, unsigned short* __restrict__ owt,
          const float* __restrict__ q, unsigned short* __restrict__ qb,
          const float* __restrict__ upd, unsigned short* __restrict__ cat,
          const float* __restrict__ gw, unsigned short* __restrict__ gwt,
          unsigned short* __restrict__ vt)
{
  __shared__ float t[32][33];
  const int b = blockIdx.x;
  const int tid = threadIdx.x;
  if (b == 0) {
    f32x4 v = *(const f32x4*)(ob + tid * 4);
    float mx = fmaxf(fmaxf(fabsf(v[0]), fabsf(v[1])), fmaxf(fabsf(v[2]), fabsf(v[3])));
#pragma unroll
    for (int off = 32; off >= 1; off >>= 1) mx = fmaxf(mx, __shfl_xor(mx, off, 64));
    __shared__ float sm[4];
    const int wid = tid >> 6, lane = tid & 63;
    if (lane == 0) sm[wid] = mx;
    __syncthreads();
    if (tid == 0) {
      float m = fmaxf(fmaxf(sm[0], sm[1]), fmaxf(sm[2], sm[3]));
      *flag = (m != 0.0f) ? 1 : 0;
    }
  } else if (b < 17) {
    f32x4 z = {};
    *(f32x4*)(zeros + (b - 1) * 1024 + tid * 4) = z;
  } else if (b < 529) {
    int idx = (b - 17) * 256 + tid;
    const float* in; unsigned short* out; int rel;
    if (idx < 65536) { in = mk; out = kb;  rel = idx; }
    else             { in = mv; out = mvb; rel = idx - 65536; }
    size_t f = (size_t)rel * 8;
    f32x4 a = *(const f32x4*)(in + f);
    f32x4 c = *(const f32x4*)(in + f + 4);
    union { unsigned short u[8]; i32x4 vec; } pk;
#pragma unroll
    for (int i = 0; i < 4; ++i) { pk.u[i] = f2bf(a[i]); pk.u[4 + i] = f2bf(c[i]); }
    *(i32x4*)(out + f) = pk.vec;
  } else if (b < 1553) {
    int id = b - 529;
    const int bx = id & 31, by = id >> 5;
    const int tx = tid & 31, ty = tid >> 5;
    const int c0 = bx * 32, r0 = by * 32;
#pragma unroll
    for (int i = 0; i < 4; ++i)
      t[ty + i * 8][tx] = ow[(size_t)(r0 + ty + i * 8) * 1024 + c0 + tx];
    __syncthreads();
#pragma unroll
    for (int i = 0; i < 4; ++i)
      owt[(size_t)(c0 + ty + i * 8) * 1024 + r0 + tx] = f2bf(t[tx][ty + i * 8]);
  } else if (b < 5649) {
    int idx = (b - 1553) * 256 + tid;
    size_t f = (size_t)idx * 8;
    f32x4 a = *(const f32x4*)(q + f);
    f32x4 c = *(const f32x4*)(q + f + 4);
    union { unsigned short u[8]; i32x4 vec; } pk;
#pragma unroll
    for (int i = 0; i < 4; ++i) { pk.u[i] = f2bf(a[i]); pk.u[4 + i] = f2bf(c[i]); }
    *(i32x4*)(qb + f) = pk.vec;
  } else {
    // gated roles: compute the need-flag locally (no intra-launch dependency)
    f32x4 v = *(const f32x4*)(ob + tid * 4);
    float mx = fmaxf(fmaxf(fabsf(v[0]), fabsf(v[1])), fmaxf(fabsf(v[2]), fabsf(v[3])));
#pragma unroll
    for (int off = 32; off >= 1; off >>= 1) mx = fmaxf(mx, __shfl_xor(mx, off, 64));
    __shared__ float sm2[4];
    const int wid = tid >> 6, lane = tid & 63;
    if (lane == 0) sm2[wid] = mx;
    __syncthreads();
    float m = fmaxf(fmaxf(sm2[0], sm2[1]), fmaxf(sm2[2], sm2[3]));
    if (m == 0.0f) return;  // fast path: gate pipeline dead through zero out-bias
    __syncthreads();
    int g = b - 5649;
    if (g < 4096) {
      int idx = g * 256 + tid;
      size_t f = (size_t)idx * 8;
      int row = (int)(f >> 10);
      int col = (int)(f & 1023);
      f32x4 a = *(const f32x4*)(upd + f);
      f32x4 c = *(const f32x4*)(upd + f + 4);
      union { unsigned short u[8]; i32x4 vec; } pk;
#pragma unroll
      for (int i = 0; i < 4; ++i) { pk.u[i] = f2bf(a[i]); pk.u[4 + i] = f2bf(c[i]); }
      *(i32x4*)(cat + (size_t)row * 2048 + 1024 + col) = pk.vec;
    } else {
      const float* in; unsigned short* out; int R, id;
      if (g < 6144) { in = gw; out = gwt; R = 2048; id = g - 4096; }
      else          { in = mv; out = vt;  R = 512;  id = g - 6144; }
      const int bx = id & 31, by = id >> 5;
      const int tx = tid & 31, ty = tid >> 5;
      const int c0 = bx * 32, r0 = by * 32;
#pragma unroll
      for (int i = 0; i < 4; ++i)
        t[ty + i * 8][tx] = in[(size_t)(r0 + ty + i * 8) * 1024 + c0 + tx];
      __syncthreads();
#pragma unroll
      for (int i = 0; i < 4; ++i)
        out[(size_t)(c0 + ty + i * 8) * R + r0 + tx] = f2bf(t[tx][ty + i * 8]);
    }
  }
}

// ---------------- L2: scores (b<512, 8-wave blocks, VGPR<=64) + w2 tail
__global__ __launch_bounds__(512, 8)
void k_scores_w2(const unsigned short* __restrict__ qb,
                 const unsigned short* __restrict__ kb,
                 const float* __restrict__ mw,
                 unsigned short* __restrict__ probs,
                 const unsigned short* __restrict__ owt,
                 const unsigned short* __restrict__ mvb,
                 float* __restrict__ w2p)
{
  __shared__ unsigned short As[128 * 64];  // 16 KB
  __shared__ unsigned short Bs[64 * 64];   //  8 KB
  const int b = blockIdx.x;
  const int tid = threadIdx.x;
  const int wid = tid >> 6, lane = tid & 63;
  const int wr = wid >> 1, wc = wid & 1;   // wr 0..3 (32-row strips), wc 0..1
  const int l15 = lane & 15, l4 = lane >> 4;

  if (b < 512) {
    const int swz = (b & 7) * 64 + (b >> 3);   // XCD swizzle
    const int bx = swz & 7, by = swz >> 3;
    const int brow = by * 128, bcol = bx * 64;
    f32x4 acc[2][2] = {};
    gemm_core<128, 64, 512>(qb, 1024, kb, 1024, 0, 1024, brow, bcol, As, Bs, acc);

    // epilogue: exp + packed bf16 stores (adjacent-lane pair -> 4B)
#pragma unroll
    for (int m = 0; m < 2; ++m) {
#pragma unroll
      for (int j = 0; j < 4; ++j) {
        int row = brow + wr * 32 + m * 16 + l4 * 4 + j;
        const float* mwrow = mw + (size_t)row * 512;
#pragma unroll
        for (int n = 0; n < 2; ++n) {
          int col = bcol + wc * 32 + n * 16 + l15;
          float p = __expf(acc[m][n][j] * 0.08838834764831845f * mwrow[col]);
          float o = __shfl_xor(p, 1);
          if (!(lane & 1)) {
            unsigned int pw = (unsigned int)f2bf(p) | ((unsigned int)f2bf(o) << 16);
            *(unsigned int*)(probs + (size_t)row * 512 + col) = pw;
          }
        }
      }
    }
  } else {
    const int g = b - 512;                 // 0..127
    const int bx = g & 7;                  // N tile (mvb rows)
    const int by = (g >> 3) & 7;           // M tile (owt rows)
    const int bz = g >> 6;                 // K slice (0..1)
    const int brow = by * 128, bcol = bx * 64;
    f32x4 acc[2][2] = {};
    gemm_core<128, 64, 512>(owt, 1024, mvb, 1024, bz * 512, bz * 512 + 512,
                            brow, bcol, As, Bs, acc);
    float* dst = w2p + (size_t)bz * 524288;
#pragma unroll
    for (int m = 0; m < 2; ++m) {
      int row0 = brow + wr * 32 + m * 16 + l4 * 4;
#pragma unroll
      for (int j = 0; j < 4; ++j) {
#pragma unroll
        for (int n = 0; n < 2; ++n)
          dst[(size_t)(row0 + j) * 512 + bcol + wc * 32 + n * 16 + l15] = acc[m][n][j];
      }
    }
  }
}

// ---------------- L3: w2 reduce (b<512) + [flag] rowsum (b in [512,2560))
//                  + [flag] read-GEMM into cat (b >= 2560, block-local rowsums)
__global__ __launch_bounds__(256)
void k_w2red_rows_read(const float* __restrict__ w2p,
                       unsigned short* __restrict__ w2t,
                       const float* __restrict__ dec,
                       const unsigned short* __restrict__ probs,
                       float* __restrict__ rowsum,
                       const unsigned short* __restrict__ vt,
                       unsigned short* __restrict__ cat,
                       const int* __restrict__ flag)
{
  __shared__ unsigned short As[128 * 64];
  __shared__ unsigned short Bs[128 * 64];
  __shared__ float srow[128];
  const int b = blockIdx.x;
  const int tid = threadIdx.x;
  if (b < 512) {
    const int i = (b * 256 + tid) * 4;
    const float d = *dec;
    f32x4 s0 = *(const f32x4*)(w2p + i);
    f32x4 s1 = *(const f32x4*)(w2p + 524288 + i);
    union { unsigned short u[4]; i32x2 v; } pk;
#pragma unroll
    for (int j = 0; j < 4; ++j) pk.u[j] = f2bf((s0[j] + s1[j]) * d);
    *(i32x2*)(w2t + i) = pk.v;
  } else if (b < 2560) {
    if (*flag == 0) return;  // rowsum only needed on the gate (slow) path
    const int wid = tid >> 6, lane = tid & 63;
    const int row = (b - 512) * 4 + wid;
    bf16x8 v = *(const bf16x8*)(probs + (size_t)row * 512 + lane * 8);
    float s = 0.0f;
#pragma unroll
    for (int i = 0; i < 8; ++i) s += bf2f((unsigned short)v[i]);
#pragma unroll
    for (int off = 32; off >= 1; off >>= 1) s += __shfl_xor(s, off, 64);
    if (lane == 0) rowsum[row] = s;
  } else {
    if (*flag == 0) return;  // read-GEMM feeds only the gate path
    const int f = b - 2560;
    const int swz = (f & 7) * 64 + (f >> 3);
    const int bx = swz & 7, by = swz >> 3;
    const int brow = by * 128, bcol = bx * 128;
    const int wid = tid >> 6, lane = tid & 63;
    const int wr = wid >> 1, wc = wid & 1;
    const int l15 = lane & 15, l4 = lane >> 4;
    f32x4 acc[4][4] = {};
    gemm_core<128, 128, 256>(probs, 512, vt, 512, 0, 512, brow, bcol, As, Bs, acc);
    // block-local rowsums (same per-row read/reduce order as the rowsum blocks)
    for (int r = 0; r < 32; ++r) {
      int lrow = wid * 32 + r;
      bf16x8 v = *(const bf16x8*)(probs + (size_t)(brow + lrow) * 512 + lane * 8);
      float s = 0.0f;
#pragma unroll
      for (int i = 0; i < 8; ++i) s += bf2f((unsigned short)v[i]);
#pragma unroll
      for (int off = 32; off >= 1; off >>= 1) s += __shfl_xor(s, off, 64);
      if (lane == 0) srow[lrow] = s;
    }
    __syncthreads();
    const float d = *dec;
#pragma unroll
    for (int m = 0; m < 4; ++m) {
      int row0 = brow + wr * 64 + m * 16 + l4 * 4;
#pragma unroll
      for (int j = 0; j < 4; ++j) {
        int row = row0 + j;
        const float rscl = d / srow[row - brow];
#pragma unroll
        for (int n = 0; n < 4; ++n) {
          int col = bcol + wc * 64 + n * 16 + l15;
          cat[(size_t)row * 2048 + col] = f2bf(acc[m][n][j] * rscl);
        }
      }
    }
  }
}

// ---------------- L4: out-projection (b<512, 8-wave) + [flag] gate GEMM (b>=512)
__global__ __launch_bounds__(512)
void k_out_gate(const unsigned short* __restrict__ probs,
                const unsigned short* __restrict__ w2t,
                const float* __restrict__ rowsum,
                unsigned short* __restrict__ outpre,
                const unsigned short* __restrict__ cat,
                const unsigned short* __restrict__ gwt,
                const float* __restrict__ gb,
                float* __restrict__ gsum,
                const int* __restrict__ flag)
{
  __shared__ unsigned short As[128 * 64];
  __shared__ unsigned short Bs[128 * 64];
  const int b = blockIdx.x;
  const int tid = threadIdx.x;
  const int wid = tid >> 6, lane = tid & 63;
  const int wr = wid >> 1, wc = wid & 1;   // wr 0..3 (32-row strips), wc 0..1
  const int l15 = lane & 15, l4 = lane >> 4;

  if (b < 512) {
    const int swz = (b & 7) * 64 + (b >> 3);
    const int bx = swz & 7, by = swz >> 3;
    const int brow = by * 128, bcol = bx * 128;
    f32x4 acc[2][4] = {};
    gemm_core<128, 128, 512>(probs, 512, w2t, 512, 0, 512, brow, bcol, As, Bs, acc);
    const bool nf = (*flag != 0);  // slow path: outpre must be exactly normalized
#pragma unroll
    for (int m = 0; m < 2; ++m) {
      int row0 = brow + wr * 32 + m * 16 + l4 * 4;
#pragma unroll
      for (int j = 0; j < 4; ++j) {
        int row = row0 + j;
        const float rscl = nf ? (1.0f / rowsum[row]) : 1.0f;
#pragma unroll
        for (int n = 0; n < 4; ++n) {
          int col = bcol + wc * 64 + n * 16 + l15;
          float v = acc[m][n][j] * rscl;
          float o = __shfl_xor(v, 1);
          if (!(lane & 1)) {
            unsigned int pw = (unsigned int)f2bf(v) | ((unsigned int)f2bf(o) << 16);
            *(unsigned int*)(outpre + (size_t)row * 1024 + col) = pw;
          }
        }
      }
    }
  } else {
    if (*flag == 0) return;
    const int f = b - 512;
    const int swz = (f & 7) * 64 + (f >> 3);
    const int bx = swz & 7, by = swz >> 3;
    const int brow = by * 128, bcol = bx * 128;
    f32x4 acc[2][4] = {};
    gemm_core<128, 128, 512>(cat, 2048, gwt, 2048, 0, 2048, brow, bcol, As, Bs, acc);
#pragma unroll
    for (int m = 0; m < 2; ++m) {
#pragma unroll
      for (int j = 0; j < 4; ++j) {
        float part = 0.0f;
#pragma unroll
        for (int n = 0; n < 4; ++n) {
          int col = bcol + wc * 64 + n * 16 + l15;
          float x = acc[m][n][j] + gb[col];
          part += 1.0f / (1.0f + __expf(-x));
        }
#pragma unroll
        for (int off = 1; off < 16; off <<= 1)
          part += __shfl_xor(part, off, 64);
        if (l15 == 0) {
          int row = brow + wr * 32 + m * 16 + l4 * 4 + j;
          atomicAdd(&gsum[row], part);
        }
      }
    }
  }
}

// ---------------- L5: LayerNorm (bf16 input), block per row
__global__ __launch_bounds__(256)
void ln_rows(const unsigned short* __restrict__ X, const float* __restrict__ gsum,
             const float* __restrict__ ob,
             const float* __restrict__ gamma, const float* __restrict__ beta,
             float* __restrict__ Y)
{
  const int row = blockIdx.x;
  const int tid = threadIdx.x;
  const size_t base = (size_t)row * 1024 + tid * 4;
  const float scl = 1.0f + gsum[row] * (1.0f / 1024.0f);
  u16x4 xr = *(const u16x4*)(X + base);
  f32x4 bo = *(const f32x4*)(ob + tid * 4);
  float x[4];
#pragma unroll
  for (int i = 0; i < 4; ++i) x[i] = bf2f(xr[i]) * scl + bo[i];
  float s = x[0] + x[1] + x[2] + x[3];
  float q = x[0] * x[0] + x[1] * x[1] + x[2] * x[2] + x[3] * x[3];
#pragma unroll
  for (int off = 32; off >= 1; off >>= 1) {
    s += __shfl_xor(s, off, 64);
    q += __shfl_xor(q, off, 64);
  }
  __shared__ float ss[4], qq[4];
  const int wid = tid >> 6, lane = tid & 63;
  if (lane == 0) { ss[wid] = s; qq[wid] = q; }
  __syncthreads();
  s = ss[0] + ss[1] + ss[2] + ss[3];
  q = qq[0] + qq[1] + qq[2] + qq[3];
  const float mu = s * (1.0f / 1024.0f);
  const float var = q * (1.0f / 1024.0f) - mu * mu;
  const float r = rsqrtf(var + 1e-5f);
  f32x4 g = *(const f32x4*)(gamma + tid * 4);
  f32x4 bt = *(const f32x4*)(beta + tid * 4);
  f32x4 y;
#pragma unroll
  for (int i = 0; i < 4; ++i) y[i] = (x[i] - mu) * r * g[i] + bt[i];
  *(f32x4*)(Y + base) = y;
}

// ---------------- launch ----------------
extern "C" void kernel_launch(void* const* d_in, const int* in_sizes, int n_in,
                              void* d_out, int out_size, void* d_ws, size_t ws_size,
                              hipStream_t stream)
{
  (void)in_sizes; (void)n_in; (void)out_size; (void)ws_size;
  const float* q   = (const float*)d_in[0];   // [8192,1024]
  const float* mw  = (const float*)d_in[1];   // [8192,512]
  const float* upd = (const float*)d_in[2];   // [8192,1024]
  const float* mk  = (const float*)d_in[3];   // [512,1024]
  const float* mv  = (const float*)d_in[4];   // [512,1024]
  const float* dec = (const float*)d_in[5];   // scalar
  const float* gw  = (const float*)d_in[6];   // [2048,1024]
  const float* gb  = (const float*)d_in[7];   // [1024]
  const float* ow  = (const float*)d_in[8];   // [1024,1024]
  const float* ob  = (const float*)d_in[9];   // [1024]
  const float* lg  = (const float*)d_in[10];  // [1024]
  const float* lb  = (const float*)d_in[11];  // [1024]
  float* outp = (float*)d_out;
  char* ws = (char*)d_ws;

  // workspace layout (bytes)
  unsigned short* qb     = (unsigned short*)(ws + 0);          // 16.78 MB
  unsigned short* probs  = (unsigned short*)(ws + 16777216);   // 8.39 MB
  unsigned short* outpre = (unsigned short*)(ws + 25165824);   // 16.78 MB
  unsigned short* kb     = (unsigned short*)(ws + 41943040);   // 1.05 MB
  unsigned short* mvb    = (unsigned short*)(ws + 42991616);   // 1.05 MB
  unsigned short* owt    = (unsigned short*)(ws + 44040192);   // 2.10 MB
  unsigned short* w2t    = (unsigned short*)(ws + 46137344);   // 1.05 MB
  float*          w2p    = (float*)(ws + 47185920);            // 4.19 MB (2 slices)
  unsigned short* vt     = (unsigned short*)(ws + 51380224);   // 1.05 MB (flag path)
  unsigned short* gwt    = (unsigned short*)(ws + 52428800);   // 4.19 MB (flag path)
  unsigned short* cat    = (unsigned short*)(ws + 56623104);   // 33.55 MB (flag path)
  float*          gsum   = (float*)(ws + 90177536);            // 32 KB
  float*          rowsum = (float*)(ws + 90210304);            // 32 KB
  int*            flag   = (int*)(ws + 90243072);              // 4 B
  // total ~90.3 MB

  // 1) prep: flag, zeroing, kb/mvb cvt, ow transpose, q cvt (+gated roles)
  prep<<<12305, 256, 0, stream>>>(ob, flag, gsum, mk, mv, kb, mvb, ow, owt,
                                  q, qb, upd, cat, gw, gwt, vt);
  // 2) scores (8-wave, VGPR<=64 -> 32 waves/CU) + w2 split-K tail
  k_scores_w2<<<640, 512, 0, stream>>>(qb, kb, mw, probs, owt, mvb, w2p);
  // 3) w2 reduce + [flag] rowsum + [flag] read-GEMM into cat
  k_w2red_rows_read<<<3072, 256, 0, stream>>>(w2p, w2t, dec, probs, rowsum,
                                              vt, cat, flag);
  // 4) out-projection (unnormalized on fast path) + [flag] gate rowsums
  k_out_gate<<<1024, 512, 0, stream>>>(probs, w2t, rowsum, outpre, cat, gwt,
                                       gb, gsum, flag);
  // 5) LayerNorm (gate scale [=1 when skipped] + out bias fused) -> final output
  ln_rows<<<8192, 256, 0, stream>>>(outpre, gsum, ob, lg, lb, outp);
}